// Round 3
// baseline (433.105 us; speedup 1.0000x reference)
//
#include <hip/hip_runtime.h>
#include <hip/hip_bf16.h>
#include <stdint.h>

#define TPB 256

using f32x4 = __attribute__((ext_vector_type(4))) float;
using s16x8 = __attribute__((ext_vector_type(8))) short;
using s16x4 = __attribute__((ext_vector_type(4))) short;

__device__ __forceinline__ short f2bf(float f){
  union { float f; uint32_t u; } v; v.f = f;
  uint32_t u = v.u;
  uint32_t r = (u + 0x7fffu + ((u >> 16) & 1u)) >> 16;
  return (short)(uint16_t)r;
}
__device__ __forceinline__ float bf2f(short b){
  union { uint32_t u; float f; } v; v.u = ((uint32_t)(uint16_t)b) << 16;
  return v.f;
}
__device__ __forceinline__ f32x4 mfma16(s16x8 a, s16x8 b, f32x4 c){
  return __builtin_amdgcn_mfma_f32_16x16x32_bf16(a, b, c, 0, 0, 0);
}

#define AS1(p) ((const __attribute__((address_space(1))) void*)(p))
#define AS3(p) ((__attribute__((address_space(3))) void*)(p))

// ---------------- fp32 -> bf16 convert ----------------
__global__ void k_cvt_bf16(const float* __restrict__ src, short* __restrict__ dst, int n8){
  int i = blockIdx.x * TPB + threadIdx.x;
  if (i >= n8) return;
  const float4* s4 = (const float4*)src;
  float4 a = s4[2*i], b = s4[2*i+1];
  s16x8 o;
  o[0]=f2bf(a.x); o[1]=f2bf(a.y); o[2]=f2bf(a.z); o[3]=f2bf(a.w);
  o[4]=f2bf(b.x); o[5]=f2bf(b.y); o[6]=f2bf(b.z); o[7]=f2bf(b.w);
  *(s16x8*)(dst + 8*(size_t)i) = o;
}

// ---------------- W (K,N) fp32 -> W^T (N,K) bf16 ----------------
__global__ void k_trans_cvt(const float* __restrict__ W, short* __restrict__ WT, int K, int Nn){
  __shared__ float ls[32][33];
  int k0 = blockIdx.x * 32, n0 = blockIdx.y * 32;
  int c = threadIdx.x & 31, i = threadIdx.x >> 5;
#pragma unroll
  for (int rr = 0; rr < 4; rr++){
    int row = i*4 + rr;
    ls[row][c] = W[(size_t)(k0+row)*Nn + n0 + c];
  }
  __syncthreads();
#pragma unroll
  for (int rr = 0; rr < 4; rr++){
    int ro = i*4 + rr;
    WT[(size_t)(n0+ro)*K + k0 + c] = f2bf(ls[c][ro]);
  }
}

// ---------------- 128x128 bf16 GEMM, BK=32, 4 waves, 3 blocks/CU ----------------
// TLP-overlap design (m114/m97 mechanism): 48 KB LDS -> 3 co-resident blocks/CU;
// one block's ds_read/stage window overlaps another's MFMA window; barriers only
// sync a block's own 4 waves. One barrier + counted vmcnt(4) per K-step; reads
// and MFMAs share a region so the compiler emits graded lgkmcnt interleave
// (measured-optimal in k_gemm8/v1; barrier-separating them cost +500 cyc/phase).
// LDS: 3 slots x 8 KB per operand; subtile layout byte(sub,row,kc) =
//   sub*1024 + kc*256 + row*16  -> stage writes and wave frag-reads are 1 KB
//   contiguous bursts (0 bank conflicts, measured R1/R2).
// Race discipline (proven in k_gemm8): stage(t)->slot (t+2)%3 == slot read at
// t-1, separated by 1 barrier + ~500cy vmem latency; reads(t) guarded by vmcnt.
template<int EPI>
__global__ void __launch_bounds__(256, 3) k_gemm128(
    const short* __restrict__ A, const short* __restrict__ Bt,
    int Nn, int K,
    const float* __restrict__ bias,
    float* __restrict__ outp,
    float* __restrict__ kvout,
    short* __restrict__ qpre, short* __restrict__ kpre, short* __restrict__ vpre)
{
  __shared__ __align__(16) short As[3][4096];
  __shared__ __align__(16) short Bs[3][4096];
  const int tid = threadIdx.x;
  const int w = tid >> 6, l = tid & 63;
  const int lrow = l & 15, lg = l >> 4;
  const int wm = w >> 1, wn = w & 1;
  // bijective XCD swizzle (nwg % 8 == 0 for both launches)
  const int nwg = (int)(gridDim.x * gridDim.y);
  const int lid = (int)blockIdx.x + (int)gridDim.x * (int)blockIdx.y;
  const int swz = (lid & 7) * (nwg >> 3) + (lid >> 3);
  const int m0 = (swz & 31) << 7, n0 = (swz >> 5) << 7;
  const int NT = K >> 5;    // BK = 32

  f32x4 acc[4][4] = {};

  // stage source mapping: linear slot s (=tid, 256+tid): sub=s>>6, kc=(s>>4)&3,
  // r=s&15 -> global row = sub*16+r, col8 = kc*8; LDS dst byte = s*16 (linear).
  const int rA0 = ((tid >> 6) << 4) + (tid & 15), cA0 = ((tid >> 4) & 3) << 3;
  const int s1  = 256 + tid;
  const int rA1 = ((s1 >> 6) << 4) + (s1 & 15),  cA1 = ((s1 >> 4) & 3) << 3;
  const size_t offA0 = (size_t)(m0 + rA0) * K + cA0;
  const size_t offA1 = (size_t)(m0 + rA1) * K + cA1;
  const size_t offB0 = (size_t)(n0 + rA0) * K + cA0;
  const size_t offB1 = (size_t)(n0 + rA1) * K + cA1;
  const int d0 = tid * 16, d1 = (256 + tid) * 16;

#define STG(sl, t_) do {                                                          \
    __builtin_amdgcn_global_load_lds(AS1(A  + offA0 + (size_t)(t_)*32),           \
                                     AS3((char*)As[sl] + d0), 16, 0, 0);          \
    __builtin_amdgcn_global_load_lds(AS1(A  + offA1 + (size_t)(t_)*32),           \
                                     AS3((char*)As[sl] + d1), 16, 0, 0);          \
    __builtin_amdgcn_global_load_lds(AS1(Bt + offB0 + (size_t)(t_)*32),           \
                                     AS3((char*)Bs[sl] + d0), 16, 0, 0);          \
    __builtin_amdgcn_global_load_lds(AS1(Bt + offB1 + (size_t)(t_)*32),           \
                                     AS3((char*)Bs[sl] + d1), 16, 0, 0);          \
  } while(0)

  // prologue: 2 K-steps in flight
  STG(0, 0);
  STG(1, 1);

  const int rdo  = lg * 256 + lrow * 16;       // bytes within a 1 KB subtile
  const int aoff = wm * 4096 + rdo;            // A subs wm*4 + mi
  const int boff = wn * 4096 + rdo;            // B subs wn*4 + ni

  int slot = 0;
  for (int t = 0; t < NT; ++t){
    if (t < NT-1) asm volatile("s_waitcnt vmcnt(4)" ::: "memory");
    else          asm volatile("s_waitcnt vmcnt(0)" ::: "memory");
    __builtin_amdgcn_s_barrier();
    asm volatile("" ::: "memory");
    const int sslot = (slot == 0) ? 2 : slot - 1;
    const char* ab = (const char*)As[slot];
    const char* bb = (const char*)Bs[slot];
    if (t + 2 < NT) STG(sslot, t+2);

    s16x8 af[4], bfr[4];
#pragma unroll
    for (int mi = 0; mi < 4; mi++)
      af[mi] = *(const s16x8*)(ab + aoff + mi*1024);
#pragma unroll
    for (int ni = 0; ni < 4; ni++)
      bfr[ni] = *(const s16x8*)(bb + boff + ni*1024);

    __builtin_amdgcn_s_setprio(1);
#pragma unroll
    for (int mi = 0; mi < 4; mi++)
#pragma unroll
      for (int ni = 0; ni < 4; ni++)
        acc[mi][ni] = mfma16(af[mi], bfr[ni], acc[mi][ni]);
    __builtin_amdgcn_s_setprio(0);

    slot = (slot == 2) ? 0 : slot + 1;
  }
#undef STG

  // epilogue (identical mapping to proven k_gemm8; per-wave 64x64)
#pragma unroll
  for (int mi = 0; mi < 4; mi++){
#pragma unroll
    for (int ni = 0; ni < 4; ni++){
      const int c  = n0 + wn*64 + ni*16 + lrow;
      const int mb = m0 + wm*64 + mi*16 + lg*4;
      const float bv = bias[c];
      if (EPI == 1){
#pragma unroll
        for (int r = 0; r < 4; r++)
          outp[(size_t)(mb+r)*Nn + c] = acc[mi][ni][r] + bv;
      } else {
        const int s = c >> 11, h = (c >> 7) & 15, tt = c & 127;
#pragma unroll
        for (int r = 0; r < 4; r++){
          const int m = mb + r;
          const int b = m >> 11, n = m & 2047;
          const int bh = b*16 + h;
          const float val = acc[mi][ni][r] + bv;
          if (s == 0){
            qpre[((size_t)bh*2048 + n)*128 + tt] = f2bf(val);
          } else if (s == 1){
            kvout[((size_t)bh*2560 + 512 + n)*128 + tt] = val;
            kpre[((size_t)bh*2048 + n)*128 + tt] = f2bf(val);
          } else {
            kvout[(size_t)(32 + bh)*327680 + (size_t)(512 + n)*128 + tt] = val;
            vpre[((size_t)bh*2048 + n)*128 + tt] = f2bf(val);
          }
        }
      }
    }
  }
}

// ---------------- RoPE kernels ----------------
__global__ void k_rope_q(const short* __restrict__ src, short* __restrict__ dst){
  int gid = blockIdx.x * TPB + threadIdx.x;
  int j = gid & 63; size_t row = gid >> 6;
  int n = (int)(row & 2047);
  float x1 = bf2f(src[row*128 + j]);
  float x2 = bf2f(src[row*128 + 64 + j]);
  float invf = __expf((float)j * (-9.210340371976184f/64.0f));
  float sn, cs; __sincosf((float)n * invf, &sn, &cs);
  const float sc = 0.088388347648318447f;   // 1/sqrt(128) folded into Q
  dst[row*128 + j]      = f2bf((x1*cs - x2*sn) * sc);
  dst[row*128 + 64 + j] = f2bf((x2*cs + x1*sn) * sc);
}

__global__ void k_rope_k_new(const short* __restrict__ kpre, short* __restrict__ kr){
  int gid = blockIdx.x * TPB + threadIdx.x;
  int j = gid & 63; size_t row = gid >> 6;
  int bh = (int)(row >> 11), n = (int)(row & 2047);
  int pos = 512 + n;
  float x1 = bf2f(kpre[row*128 + j]);
  float x2 = bf2f(kpre[row*128 + 64 + j]);
  float invf = __expf((float)j * (-9.210340371976184f/64.0f));
  float sn, cs; __sincosf((float)pos * invf, &sn, &cs);
  size_t drow = (size_t)bh*2560 + pos;
  kr[drow*128 + j]      = f2bf(x1*cs - x2*sn);
  kr[drow*128 + 64 + j] = f2bf(x2*cs + x1*sn);
}

__global__ void k_rope_k_prefix(const float* __restrict__ pk, float* __restrict__ kvout0,
                                short* __restrict__ kr){
  int gid = blockIdx.x * TPB + threadIdx.x;
  int j = gid & 63; size_t row = gid >> 6;
  int bh = (int)(row >> 9), p = (int)(row & 511);
  float x1 = pk[row*128 + j];
  float x2 = pk[row*128 + 64 + j];
  size_t orow = (size_t)bh*2560 + p;
  kvout0[orow*128 + j]      = x1;
  kvout0[orow*128 + 64 + j] = x2;
  float invf = __expf((float)j * (-9.210340371976184f/64.0f));
  float sn, cs; __sincosf((float)p * invf, &sn, &cs);
  kr[orow*128 + j]      = f2bf(x1*cs - x2*sn);
  kr[orow*128 + 64 + j] = f2bf(x2*cs + x1*sn);
}

// ---------------- V transpose: build V^T (b,h,d,key) bf16 ----------------
__global__ void k_v_prefix(const float* __restrict__ pv, float* __restrict__ kvout1,
                           short* __restrict__ vT){
  __shared__ float ls[32][129];
  int bh = blockIdx.x >> 4, pt = blockIdx.x & 15;
  int p0 = pt*32, tid = threadIdx.x;
#pragma unroll
  for (int i = 0; i < 16; i++){
    int idx = i*TPB + tid; int p = idx >> 7, t = idx & 127;
    float v = pv[((size_t)bh*512 + p0 + p)*128 + t];
    ls[p][t] = v;
    kvout1[((size_t)bh*2560 + p0 + p)*128 + t] = v;
  }
  __syncthreads();
#pragma unroll
  for (int i = 0; i < 16; i++){
    int idx = i*TPB + tid; int t = idx >> 5, p = idx & 31;
    vT[((size_t)bh*128 + t)*2560 + p0 + p] = f2bf(ls[p][t]);
  }
}

__global__ void k_v_new(const short* __restrict__ vpre, short* __restrict__ vT){
  __shared__ float ls[32][129];
  int bh = blockIdx.x >> 6, nt = blockIdx.x & 63;
  int n0 = nt*32, tid = threadIdx.x;
#pragma unroll
  for (int i = 0; i < 16; i++){
    int idx = i*TPB + tid; int p = idx >> 7, t = idx & 127;
    ls[p][t] = bf2f(vpre[((size_t)bh*2048 + n0 + p)*128 + t]);
  }
  __syncthreads();
#pragma unroll
  for (int i = 0; i < 16; i++){
    int idx = i*TPB + tid; int t = idx >> 5, p = idx & 31;
    vT[((size_t)bh*128 + t)*2560 + 512 + n0 + p] = f2bf(ls[p][t]);
  }
}

// ---------------- flash attention, v3: swapped QK^T + balanced pairs ----------------
__global__ void __launch_bounds__(256, 2) k_attn(
    const short* __restrict__ qr, const short* __restrict__ kr,
    const short* __restrict__ vT, short* __restrict__ attno)
{
  __shared__ short Ks[2][64*128];
  __shared__ short VTs[2][128*64];
  __shared__ short Ps[4][16*64];
  const int bh = blockIdx.x;
  const int pA = blockIdx.y, pB = 31 - pA;
  const int nA = 9 + pA, nTot = 49;
  const int tid = threadIdx.x, w = tid >> 6, l = tid & 63;
  const int lrow = l & 15, lg = l >> 4;
  const int b = bh >> 4, h = bh & 15;

  s16x8 qfA[4], qfB[4];
  {
    const size_t rA = (size_t)bh*2048 + pA*64 + w*16 + lrow;
    const size_t rB = (size_t)bh*2048 + pB*64 + w*16 + lrow;
#pragma unroll
    for (int ks = 0; ks < 4; ks++){
      qfA[ks] = *(const s16x8*)&qr[rA*128 + ks*32 + lg*8];
      qfB[ks] = *(const s16x8*)&qr[rB*128 + ks*32 + lg*8];
    }
  }

#define STAGE_KV(buf, kv0s) do {                                                    \
    _Pragma("unroll")                                                               \
    for (int i_ = 0; i_ < 4; i_++){                                                 \
      int chunk = i_*256 + tid;                                                     \
      int row = chunk >> 4, cc = (chunk & 15) ^ (row & 7);                          \
      __builtin_amdgcn_global_load_lds(                                             \
        AS1(kr + ((size_t)bh*2560 + (kv0s) + row)*128 + cc*8),                      \
        AS3((char*)Ks[buf] + (i_*256 + w*64)*16), 16, 0, 0);                        \
    }                                                                               \
    _Pragma("unroll")                                                               \
    for (int i_ = 0; i_ < 4; i_++){                                                 \
      int chunk = i_*256 + tid;                                                     \
      int row = chunk >> 3, cc = (chunk & 7) ^ (row & 7);                           \
      __builtin_amdgcn_global_load_lds(                                             \
        AS1(vT + ((size_t)bh*128 + row)*2560 + (kv0s) + cc*8),                      \
        AS3((char*)VTs[buf] + (i_*256 + w*64)*16), 16, 0, 0);                       \
    }                                                                               \
  } while(0)

  STAGE_KV(0, 0);
  STAGE_KV(1, 64);

  char* psw = (char*)&Ps[w][0];
  int g = 0;
#pragma unroll 2
  for (int ph = 0; ph < 2; ph++){
    const int qt = ph ? pB : pA;
    const int n = 9 + qt;
    const int qbw = qt*64 + w*16;
    f32x4 acc[8] = {};
    float mr = -1e30f, lsum = 0.f;

    for (int t = 0; t < n; t++, g++){
      if (g+1 < nTot) asm volatile("s_waitcnt vmcnt(8)" ::: "memory");
      else            asm volatile("s_waitcnt vmcnt(0)" ::: "memory");
      __builtin_amdgcn_s_barrier();
      asm volatile("" ::: "memory");
      const char* kb_ = (const char*)Ks[g&1];
      const char* vb_ = (const char*)VTs[g&1];
      const int kv0 = t*64;

      f32x4 sf[4];
      __builtin_amdgcn_s_setprio(1);
#pragma unroll
      for (int kb = 0; kb < 4; kb++){
        f32x4 s = {0.f,0.f,0.f,0.f};
#pragma unroll
        for (int ks = 0; ks < 4; ks++){
          int row  = kb*16 + lrow;
          int colb = ks*64 + lg*16;
          s16x8 kf = *(const s16x8*)(kb_ + row*256 + (colb ^ ((row&7)<<4)));
          s = mfma16(kf, ph ? qfB[ks] : qfA[ks], s);
        }
        sf[kb] = s;
      }
      __builtin_amdgcn_s_setprio(0);

      const int qme = 512 + qbw + lrow;
      if (kv0 + 63 > 512 + qbw){
#pragma unroll
        for (int kb = 0; kb < 4; kb++)
#pragma unroll
          for (int r = 0; r < 4; r++){
            int kg = kv0 + kb*16 + lg*4 + r;
            if (kg > qme) sf[kb][r] = -1e30f;
          }
      }

      float m_ = fmaxf(
          fmaxf(fmaxf(fmaxf(sf[0][0],sf[0][1]),fmaxf(sf[0][2],sf[0][3])),
                fmaxf(fmaxf(sf[1][0],sf[1][1]),fmaxf(sf[1][2],sf[1][3]))),
          fmaxf(fmaxf(fmaxf(sf[2][0],sf[2][1]),fmaxf(sf[2][2],sf[2][3])),
                fmaxf(fmaxf(sf[3][0],sf[3][1]),fmaxf(sf[3][2],sf[3][3]))));
      m_ = fmaxf(m_, __shfl_xor(m_, 16));
      m_ = fmaxf(m_, __shfl_xor(m_, 32));

      if (__any(m_ > mr + 8.f)){
        float mnew = fmaxf(mr, m_);
        float sc = __expf(mr - mnew);
        mr = mnew;
        lsum *= sc;
        float scr[4];
#pragma unroll
        for (int r = 0; r < 4; r++)
          scr[r] = __shfl(sc, (l & 48) | (lg*4 + r));
#pragma unroll
        for (int dt = 0; dt < 8; dt++)
#pragma unroll
          for (int r = 0; r < 4; r++) acc[dt][r] *= scr[r];
      }

#pragma unroll
      for (int kb = 0; kb < 4; kb++){
        float p0 = __expf(sf[kb][0] - mr);
        float p1 = __expf(sf[kb][1] - mr);
        float p2 = __expf(sf[kb][2] - mr);
        float p3 = __expf(sf[kb][3] - mr);
        lsum += (p0+p1)+(p2+p3);
        s16x4 pk4 = { f2bf(p0), f2bf(p1), f2bf(p2), f2bf(p3) };
        *(s16x4*)(psw + (lrow*128 + ((kb*32 + lg*8) ^ ((lrow&7)<<4)))) = pk4;
      }

      __builtin_amdgcn_s_setprio(1);
#pragma unroll
      for (int kp = 0; kp < 2; kp++){
        s16x8 pa = *(const s16x8*)(psw + (lrow*128 + ((kp*64 + lg*16) ^ ((lrow&7)<<4))));
#pragma unroll
        for (int dt = 0; dt < 8; dt++){
          int vrow = dt*16 + lrow;
          int vcolb = kp*64 + lg*16;
          s16x8 vf = *(const s16x8*)(vb_ + vrow*128 + (vcolb ^ ((vrow&7)<<4)));
          acc[dt] = mfma16(pa, vf, acc[dt]);
        }
      }
      __builtin_amdgcn_s_setprio(0);

      asm volatile("" ::: "memory");
      __builtin_amdgcn_s_barrier();
      asm volatile("" ::: "memory");
      const int gg = g + 2;
      if (gg < nTot){
        const int kvs = (gg < nA ? gg : gg - nA) * 64;
        STAGE_KV(g&1, kvs);
      }
    }

    float ls_ = lsum;
    ls_ += __shfl_xor(ls_, 16);
    ls_ += __shfl_xor(ls_, 32);
    float linv[4];
#pragma unroll
    for (int r = 0; r < 4; r++)
      linv[r] = 1.f / __shfl(ls_, (l & 48) | (lg*4 + r));
#pragma unroll
    for (int dt = 0; dt < 8; dt++){
#pragma unroll
      for (int r = 0; r < 4; r++){
        int nrow = qbw + lg*4 + r;
        int dcol = h*128 + dt*16 + lrow;
        attno[((size_t)b*2048 + nrow)*2048 + dcol] = f2bf(acc[dt][r] * linv[r]);
      }
    }
  }
#undef STAGE_KV
}

// ---------------- launch ----------------
extern "C" void kernel_launch(void* const* d_in, const int* in_sizes, int n_in,
                              void* d_out, int out_size, void* d_ws, size_t ws_size,
                              hipStream_t stream)
{
  const float* x    = (const float*)d_in[0];
  const float* pk   = (const float*)d_in[2];
  const float* pv   = (const float*)d_in[3];
  const float* Wqkv = (const float*)d_in[4];
  const float* bqkv = (const float*)d_in[5];
  const float* Wff  = (const float*)d_in[6];
  const float* bff  = (const float*)d_in[7];
  float* out   = (float*)d_out;
  float* kvout = out + 8388608;

  char* ws = (char*)d_ws;
  short* xb    = (short*)(ws);
  short* wqkvT = (short*)(ws + 16777216);
  short* wffT  = (short*)(ws + 41943040);
  short* qpre  = (short*)(ws + 50331648);
  short* kpre  = (short*)(ws + 67108864);
  short* vpre  = (short*)(ws + 83886080);
  short* qrp   = (short*)(ws + 100663296);
  short* krp   = (short*)(ws + 117440512);
  short* vTp   = (short*)(ws + 138412032);
  short* attno = (short*)(ws + 159383552);

  k_cvt_bf16<<<4096, TPB, 0, stream>>>(x, xb, 1048576);
  k_trans_cvt<<<dim3(64, 192), TPB, 0, stream>>>(Wqkv, wqkvT, 2048, 6144);
  k_trans_cvt<<<dim3(64, 64),  TPB, 0, stream>>>(Wff,  wffT,  2048, 2048);

  k_gemm128<0><<<dim3(32, 48), 256, 0, stream>>>(xb, wqkvT, 6144, 2048, bqkv,
                                                 nullptr, kvout, qpre, kpre, vpre);

  k_rope_q<<<16384, TPB, 0, stream>>>(qpre, qrp);
  k_rope_k_new<<<16384, TPB, 0, stream>>>(kpre, krp);
  k_rope_k_prefix<<<4096, TPB, 0, stream>>>(pk, kvout, krp);
  k_v_prefix<<<512, TPB, 0, stream>>>(pv, kvout + (size_t)32*327680, vTp);
  k_v_new<<<2048, TPB, 0, stream>>>(vpre, vTp);

  k_attn<<<dim3(32, 16), TPB, 0, stream>>>(qrp, krp, vTp, attno);

  k_gemm128<1><<<dim3(32, 16), 256, 0, stream>>>(attno, wffT, 2048, 2048, bff,
                                                 out, nullptr, nullptr, nullptr, nullptr);
}

// Round 4
// 307.079 us; speedup vs baseline: 1.4104x; 1.4104x over previous
//
#include <hip/hip_runtime.h>
#include <hip/hip_bf16.h>
#include <stdint.h>

#define TPB 256

using f32x4 = __attribute__((ext_vector_type(4))) float;
using s16x8 = __attribute__((ext_vector_type(8))) short;
using s16x4 = __attribute__((ext_vector_type(4))) short;

__device__ __forceinline__ short f2bf(float f){
  union { float f; uint32_t u; } v; v.f = f;
  uint32_t u = v.u;
  uint32_t r = (u + 0x7fffu + ((u >> 16) & 1u)) >> 16;
  return (short)(uint16_t)r;
}
__device__ __forceinline__ float bf2f(short b){
  union { uint32_t u; float f; } v; v.u = ((uint32_t)(uint16_t)b) << 16;
  return v.f;
}
__device__ __forceinline__ f32x4 mfma16(s16x8 a, s16x8 b, f32x4 c){
  return __builtin_amdgcn_mfma_f32_16x16x32_bf16(a, b, c, 0, 0, 0);
}

#define AS1(p) ((const __attribute__((address_space(1))) void*)(p))
#define AS3(p) ((__attribute__((address_space(3))) void*)(p))

// ---------------- fp32 -> bf16 convert ----------------
__global__ void k_cvt_bf16(const float* __restrict__ src, short* __restrict__ dst, int n8){
  int i = blockIdx.x * TPB + threadIdx.x;
  if (i >= n8) return;
  const float4* s4 = (const float4*)src;
  float4 a = s4[2*i], b = s4[2*i+1];
  s16x8 o;
  o[0]=f2bf(a.x); o[1]=f2bf(a.y); o[2]=f2bf(a.z); o[3]=f2bf(a.w);
  o[4]=f2bf(b.x); o[5]=f2bf(b.y); o[6]=f2bf(b.z); o[7]=f2bf(b.w);
  *(s16x8*)(dst + 8*(size_t)i) = o;
}

// ---------------- W (K,N) fp32 -> W^T (N,K) bf16 ----------------
__global__ void k_trans_cvt(const float* __restrict__ W, short* __restrict__ WT, int K, int Nn){
  __shared__ float ls[32][33];
  int k0 = blockIdx.x * 32, n0 = blockIdx.y * 32;
  int c = threadIdx.x & 31, i = threadIdx.x >> 5;
#pragma unroll
  for (int rr = 0; rr < 4; rr++){
    int row = i*4 + rr;
    ls[row][c] = W[(size_t)(k0+row)*Nn + n0 + c];
  }
  __syncthreads();
#pragma unroll
  for (int rr = 0; rr < 4; rr++){
    int ro = i*4 + rr;
    WT[(size_t)(n0+ro)*K + k0 + c] = f2bf(ls[c][ro]);
  }
}

// ---------------- 256x128 bf16 GEMM, 3-slot LDS rotation, counted vmcnt ----------------
// Round-0 verified structure (12.4 cyc/MFMA — best of 4 variants measured across
// rounds 0-3; the 256^2 2-phase, 4-phase barrier-split, and 128^2 3-block/CU TLP
// variants all regressed). Do not barrier-separate ds_reads from MFMAs (costs
// +500 cyc/phase); do not shrink the tile (fixed per-step overhead dominates).
template<int EPI>
__global__ void __launch_bounds__(512, 2) k_gemm8(
    const short* __restrict__ A, const short* __restrict__ Bt,
    int Nn, int K,
    const float* __restrict__ bias,
    float* __restrict__ outp,
    float* __restrict__ kvout,
    short* __restrict__ qpre, short* __restrict__ kpre, short* __restrict__ vpre)
{
  __shared__ __align__(16) short As[3][16384];
  __shared__ __align__(16) short Bs[3][8192];
  const int tid = threadIdx.x;
  const int w = tid >> 6, l = tid & 63;
  const int lrow = l & 15, lg = l >> 4;
  const int wm = w >> 1, wn = w & 1;
  const int m0 = blockIdx.x << 8, n0 = blockIdx.y << 7;
  const int NT = K >> 6;

  f32x4 acc[4][4] = {};

#define STAGE_A(slot, t, j) do {                                             \
    int chunk = ((w*4 + (j)) << 6) + l;                                      \
    int row = chunk >> 3, cc = chunk & 7;                                    \
    __builtin_amdgcn_global_load_lds(                                        \
      AS1(A + (size_t)(m0+row)*K + (t)*64 + ((cc ^ (row&7)) << 3)),          \
      AS3(&As[slot][(w*4 + (j)) << 9]), 16, 0, 0);                           \
  } while(0)
#define STAGE_B(slot, t, j) do {                                             \
    int chunk = ((w*2 + (j)) << 6) + l;                                      \
    int row = chunk >> 3, cc = chunk & 7;                                    \
    __builtin_amdgcn_global_load_lds(                                        \
      AS1(Bt + (size_t)(n0+row)*K + (t)*64 + ((cc ^ (row&7)) << 3)),         \
      AS3(&Bs[slot][(w*2 + (j)) << 9]), 16, 0, 0);                           \
  } while(0)

  STAGE_A(0,0,0); STAGE_A(0,0,1); STAGE_A(0,0,2); STAGE_A(0,0,3);
  STAGE_B(0,0,0); STAGE_B(0,0,1);
  STAGE_A(1,1,0); STAGE_A(1,1,1); STAGE_A(1,1,2); STAGE_A(1,1,3);
  STAGE_B(1,1,0); STAGE_B(1,1,1);

  int slot = 0;
  for (int t = 0; t < NT; ++t){
    if (t < NT-1) asm volatile("s_waitcnt vmcnt(6)" ::: "memory");
    else          asm volatile("s_waitcnt vmcnt(0)" ::: "memory");
    __builtin_amdgcn_s_barrier();
    asm volatile("" ::: "memory");
    const int sslot = (slot == 0) ? 2 : slot - 1;
    const bool st = (t+2) < NT;
    const char* ab = (const char*)As[slot];
    const char* bb = (const char*)Bs[slot];

    s16x8 bfr[4][2];
#pragma unroll
    for (int ni = 0; ni < 4; ni++){
      int row = wn*64 + ni*16 + lrow;
#pragma unroll
      for (int ks = 0; ks < 2; ks++)
        bfr[ni][ks] = *(const s16x8*)(bb + row*128 + ((ks*64 + lg*16) ^ ((row&7)<<4)));
    }
    s16x8 af[2][2];
#pragma unroll
    for (int mi = 0; mi < 2; mi++){
      int row = wm*64 + mi*16 + lrow;
#pragma unroll
      for (int ks = 0; ks < 2; ks++)
        af[mi][ks] = *(const s16x8*)(ab + row*128 + ((ks*64 + lg*16) ^ ((row&7)<<4)));
    }
    if (st){ STAGE_A(sslot,t+2,0); STAGE_A(sslot,t+2,1); STAGE_B(sslot,t+2,0); }
    __builtin_amdgcn_s_setprio(1);
#pragma unroll
    for (int ks = 0; ks < 2; ks++)
#pragma unroll
      for (int mi = 0; mi < 2; mi++)
#pragma unroll
        for (int ni = 0; ni < 4; ni++)
          acc[mi][ni] = mfma16(af[mi][ks], bfr[ni][ks], acc[mi][ni]);
    __builtin_amdgcn_s_setprio(0);
    asm volatile("" ::: "memory");
    __builtin_amdgcn_s_barrier();
    asm volatile("" ::: "memory");

    s16x8 af2[2][2];
#pragma unroll
    for (int mi = 0; mi < 2; mi++){
      int row = wm*64 + (mi+2)*16 + lrow;
#pragma unroll
      for (int ks = 0; ks < 2; ks++)
        af2[mi][ks] = *(const s16x8*)(ab + row*128 + ((ks*64 + lg*16) ^ ((row&7)<<4)));
    }
    if (st){ STAGE_A(sslot,t+2,2); STAGE_A(sslot,t+2,3); STAGE_B(sslot,t+2,1); }
    __builtin_amdgcn_s_setprio(1);
#pragma unroll
    for (int ks = 0; ks < 2; ks++)
#pragma unroll
      for (int mi = 0; mi < 2; mi++)
#pragma unroll
        for (int ni = 0; ni < 4; ni++)
          acc[mi+2][ni] = mfma16(af2[mi][ks], bfr[ni][ks], acc[mi+2][ni]);
    __builtin_amdgcn_s_setprio(0);
    slot = (slot == 2) ? 0 : slot + 1;
  }
#undef STAGE_A
#undef STAGE_B

#pragma unroll
  for (int mi = 0; mi < 4; mi++){
#pragma unroll
    for (int ni = 0; ni < 4; ni++){
      const int c  = n0 + wn*64 + ni*16 + lrow;
      const int mb = m0 + wm*64 + mi*16 + lg*4;
      const float bv = bias[c];
      if (EPI == 1){
#pragma unroll
        for (int r = 0; r < 4; r++)
          outp[(size_t)(mb+r)*Nn + c] = acc[mi][ni][r] + bv;
      } else {
        const int s = c >> 11, h = (c >> 7) & 15, tt = c & 127;
#pragma unroll
        for (int r = 0; r < 4; r++){
          const int m = mb + r;
          const int b = m >> 11, n = m & 2047;
          const int bh = b*16 + h;
          const float val = acc[mi][ni][r] + bv;
          if (s == 0){
            qpre[((size_t)bh*2048 + n)*128 + tt] = f2bf(val);
          } else if (s == 1){
            kvout[((size_t)bh*2560 + 512 + n)*128 + tt] = val;
            kpre[((size_t)bh*2048 + n)*128 + tt] = f2bf(val);
          } else {
            kvout[(size_t)(32 + bh)*327680 + (size_t)(512 + n)*128 + tt] = val;
            vpre[((size_t)bh*2048 + n)*128 + tt] = f2bf(val);
          }
        }
      }
    }
  }
}

// ---------------- RoPE-K kernels (vectorized: s16x8 / float4 loads, G13) ----------------
__global__ void k_rope_k_new(const short* __restrict__ kpre, short* __restrict__ kr){
  int gid = blockIdx.x * TPB + threadIdx.x;        // 65536 rows * 8 threads
  int jb = (gid & 7) * 8; size_t row = gid >> 3;
  int bh = (int)(row >> 11), n = (int)(row & 2047);
  int pos = 512 + n;
  s16x8 v1 = *(const s16x8*)&kpre[row*128 + jb];
  s16x8 v2 = *(const s16x8*)&kpre[row*128 + 64 + jb];
  s16x8 o1, o2;
#pragma unroll
  for (int e = 0; e < 8; e++){
    float invf = __expf((float)(jb + e) * (-9.210340371976184f/64.0f));
    float sn, cs; __sincosf((float)pos * invf, &sn, &cs);
    float x1 = bf2f(v1[e]), x2 = bf2f(v2[e]);
    o1[e] = f2bf(x1*cs - x2*sn);
    o2[e] = f2bf(x2*cs + x1*sn);
  }
  size_t drow = (size_t)bh*2560 + pos;
  *(s16x8*)&kr[drow*128 + jb]      = o1;
  *(s16x8*)&kr[drow*128 + 64 + jb] = o2;
}

__global__ void k_rope_k_prefix(const float* __restrict__ pk, float* __restrict__ kvout0,
                                short* __restrict__ kr){
  int gid = blockIdx.x * TPB + threadIdx.x;        // 16384 rows * 8 threads
  int jb = (gid & 7) * 8; size_t row = gid >> 3;
  int bh = (int)(row >> 9), p = (int)(row & 511);
  float4 a1 = *(const float4*)&pk[row*128 + jb];
  float4 a2 = *(const float4*)&pk[row*128 + jb + 4];
  float4 b1 = *(const float4*)&pk[row*128 + 64 + jb];
  float4 b2 = *(const float4*)&pk[row*128 + 64 + jb + 4];
  size_t orow = (size_t)bh*2560 + p;
  *(float4*)&kvout0[orow*128 + jb]          = a1;
  *(float4*)&kvout0[orow*128 + jb + 4]      = a2;
  *(float4*)&kvout0[orow*128 + 64 + jb]     = b1;
  *(float4*)&kvout0[orow*128 + 64 + jb + 4] = b2;
  float x1[8] = {a1.x,a1.y,a1.z,a1.w,a2.x,a2.y,a2.z,a2.w};
  float x2[8] = {b1.x,b1.y,b1.z,b1.w,b2.x,b2.y,b2.z,b2.w};
  s16x8 o1, o2;
#pragma unroll
  for (int e = 0; e < 8; e++){
    float invf = __expf((float)(jb + e) * (-9.210340371976184f/64.0f));
    float sn, cs; __sincosf((float)p * invf, &sn, &cs);
    o1[e] = f2bf(x1[e]*cs - x2[e]*sn);
    o2[e] = f2bf(x2[e]*cs + x1[e]*sn);
  }
  *(s16x8*)&kr[orow*128 + jb]      = o1;
  *(s16x8*)&kr[orow*128 + 64 + jb] = o2;
}

// ---------------- V transpose: build V^T (b,h,d,key) bf16 ----------------
__global__ void k_v_prefix(const float* __restrict__ pv, float* __restrict__ kvout1,
                           short* __restrict__ vT){
  __shared__ float ls[32][129];
  int bh = blockIdx.x >> 4, pt = blockIdx.x & 15;
  int p0 = pt*32, tid = threadIdx.x;
#pragma unroll
  for (int i = 0; i < 16; i++){
    int idx = i*TPB + tid; int p = idx >> 7, t = idx & 127;
    float v = pv[((size_t)bh*512 + p0 + p)*128 + t];
    ls[p][t] = v;
    kvout1[((size_t)bh*2560 + p0 + p)*128 + t] = v;
  }
  __syncthreads();
#pragma unroll
  for (int i = 0; i < 16; i++){
    int idx = i*TPB + tid; int t = idx >> 5, p = idx & 31;
    vT[((size_t)bh*128 + t)*2560 + p0 + p] = f2bf(ls[p][t]);
  }
}

__global__ void k_v_new(const short* __restrict__ vpre, short* __restrict__ vT){
  __shared__ float ls[32][129];
  int bh = blockIdx.x >> 6, nt = blockIdx.x & 63;
  int n0 = nt*32, tid = threadIdx.x;
#pragma unroll
  for (int i = 0; i < 16; i++){
    int idx = i*TPB + tid; int p = idx >> 7, t = idx & 127;
    ls[p][t] = bf2f(vpre[((size_t)bh*2048 + n0 + p)*128 + t]);
  }
  __syncthreads();
#pragma unroll
  for (int i = 0; i < 16; i++){
    int idx = i*TPB + tid; int t = idx >> 5, p = idx & 31;
    vT[((size_t)bh*128 + t)*2560 + 512 + n0 + p] = f2bf(ls[p][t]);
  }
}

// ---------------- flash attention: swapped QK^T + balanced pairs + fused RoPE-Q ----------------
// RoPE-Q fused into the Q preload: lane's fragment covers cols c = ks*32+lg*8+e;
// the RoPE partner of c<64 is c+64 = (ks+2)*32+lg*8+e -> SAME lane, qf[ks]<->qf[ks+2].
// 32 sincos/lane once per block (~1k cyc vs ~257k cyc/block). Eliminates the
// k_rope_q kernel (33.6 MB HBM roundtrip). Numerically identical to the
// standalone kernel (same bf16 input, rotation in fp32, one f2bf at the end).
__global__ void __launch_bounds__(256, 2) k_attn(
    const short* __restrict__ qr, const short* __restrict__ kr,
    const short* __restrict__ vT, short* __restrict__ attno)
{
  __shared__ short Ks[2][64*128];
  __shared__ short VTs[2][128*64];
  __shared__ short Ps[4][16*64];
  const int bh = blockIdx.x;
  const int pA = blockIdx.y, pB = 31 - pA;
  const int nA = 9 + pA, nTot = 49;
  const int tid = threadIdx.x, w = tid >> 6, l = tid & 63;
  const int lrow = l & 15, lg = l >> 4;
  const int b = bh >> 4, h = bh & 15;

  s16x8 qfA[4], qfB[4];
  {
    const int nAr = pA*64 + w*16 + lrow;     // query position (row in [0,2048))
    const int nBr = pB*64 + w*16 + lrow;
    const size_t rA = (size_t)bh*2048 + nAr;
    const size_t rB = (size_t)bh*2048 + nBr;
#pragma unroll
    for (int ks = 0; ks < 4; ks++){
      qfA[ks] = *(const s16x8*)&qr[rA*128 + ks*32 + lg*8];
      qfB[ks] = *(const s16x8*)&qr[rB*128 + ks*32 + lg*8];
    }
    const float sc = 0.088388347648318447f;  // 1/sqrt(128) folded into Q
#pragma unroll
    for (int ks = 0; ks < 2; ks++){
#pragma unroll
      for (int e = 0; e < 8; e++){
        const int j = ks*32 + lg*8 + e;      // j in [0,64)
        const float invf = __expf((float)j * (-9.210340371976184f/64.0f));
        float sn, cs;
        __sincosf((float)nAr * invf, &sn, &cs);
        float x1 = bf2f(qfA[ks][e]), x2 = bf2f(qfA[ks+2][e]);
        qfA[ks][e]   = f2bf((x1*cs - x2*sn) * sc);
        qfA[ks+2][e] = f2bf((x2*cs + x1*sn) * sc);
        __sincosf((float)nBr * invf, &sn, &cs);
        float y1 = bf2f(qfB[ks][e]), y2 = bf2f(qfB[ks+2][e]);
        qfB[ks][e]   = f2bf((y1*cs - y2*sn) * sc);
        qfB[ks+2][e] = f2bf((y2*cs + y1*sn) * sc);
      }
    }
  }

#define STAGE_KV(buf, kv0s) do {                                                    \
    _Pragma("unroll")                                                               \
    for (int i_ = 0; i_ < 4; i_++){                                                 \
      int chunk = i_*256 + tid;                                                     \
      int row = chunk >> 4, cc = (chunk & 15) ^ (row & 7);                          \
      __builtin_amdgcn_global_load_lds(                                             \
        AS1(kr + ((size_t)bh*2560 + (kv0s) + row)*128 + cc*8),                      \
        AS3((char*)Ks[buf] + (i_*256 + w*64)*16), 16, 0, 0);                        \
    }                                                                               \
    _Pragma("unroll")                                                               \
    for (int i_ = 0; i_ < 4; i_++){                                                 \
      int chunk = i_*256 + tid;                                                     \
      int row = chunk >> 3, cc = (chunk & 7) ^ (row & 7);                           \
      __builtin_amdgcn_global_load_lds(                                             \
        AS1(vT + ((size_t)bh*128 + row)*2560 + (kv0s) + cc*8),                      \
        AS3((char*)VTs[buf] + (i_*256 + w*64)*16), 16, 0, 0);                       \
    }                                                                               \
  } while(0)

  STAGE_KV(0, 0);
  STAGE_KV(1, 64);

  char* psw = (char*)&Ps[w][0];
  int g = 0;
#pragma unroll 2
  for (int ph = 0; ph < 2; ph++){
    const int qt = ph ? pB : pA;
    const int n = 9 + qt;
    const int qbw = qt*64 + w*16;
    f32x4 acc[8] = {};
    float mr = -1e30f, lsum = 0.f;

    for (int t = 0; t < n; t++, g++){
      if (g+1 < nTot) asm volatile("s_waitcnt vmcnt(8)" ::: "memory");
      else            asm volatile("s_waitcnt vmcnt(0)" ::: "memory");
      __builtin_amdgcn_s_barrier();
      asm volatile("" ::: "memory");
      const char* kb_ = (const char*)Ks[g&1];
      const char* vb_ = (const char*)VTs[g&1];
      const int kv0 = t*64;

      f32x4 sf[4];
      __builtin_amdgcn_s_setprio(1);
#pragma unroll
      for (int kb = 0; kb < 4; kb++){
        f32x4 s = {0.f,0.f,0.f,0.f};
#pragma unroll
        for (int ks = 0; ks < 4; ks++){
          int row  = kb*16 + lrow;
          int colb = ks*64 + lg*16;
          s16x8 kf = *(const s16x8*)(kb_ + row*256 + (colb ^ ((row&7)<<4)));
          s = mfma16(kf, ph ? qfB[ks] : qfA[ks], s);
        }
        sf[kb] = s;
      }
      __builtin_amdgcn_s_setprio(0);

      const int qme = 512 + qbw + lrow;
      if (kv0 + 63 > 512 + qbw){
#pragma unroll
        for (int kb = 0; kb < 4; kb++)
#pragma unroll
          for (int r = 0; r < 4; r++){
            int kg = kv0 + kb*16 + lg*4 + r;
            if (kg > qme) sf[kb][r] = -1e30f;
          }
      }

      float m_ = fmaxf(
          fmaxf(fmaxf(fmaxf(sf[0][0],sf[0][1]),fmaxf(sf[0][2],sf[0][3])),
                fmaxf(fmaxf(sf[1][0],sf[1][1]),fmaxf(sf[1][2],sf[1][3]))),
          fmaxf(fmaxf(fmaxf(sf[2][0],sf[2][1]),fmaxf(sf[2][2],sf[2][3])),
                fmaxf(fmaxf(sf[3][0],sf[3][1]),fmaxf(sf[3][2],sf[3][3]))));
      m_ = fmaxf(m_, __shfl_xor(m_, 16));
      m_ = fmaxf(m_, __shfl_xor(m_, 32));

      if (__any(m_ > mr + 8.f)){
        float mnew = fmaxf(mr, m_);
        float sc = __expf(mr - mnew);
        mr = mnew;
        lsum *= sc;
        float scr[4];
#pragma unroll
        for (int r = 0; r < 4; r++)
          scr[r] = __shfl(sc, (l & 48) | (lg*4 + r));
#pragma unroll
        for (int dt = 0; dt < 8; dt++)
#pragma unroll
          for (int r = 0; r < 4; r++) acc[dt][r] *= scr[r];
      }

#pragma unroll
      for (int kb = 0; kb < 4; kb++){
        float p0 = __expf(sf[kb][0] - mr);
        float p1 = __expf(sf[kb][1] - mr);
        float p2 = __expf(sf[kb][2] - mr);
        float p3 = __expf(sf[kb][3] - mr);
        lsum += (p0+p1)+(p2+p3);
        s16x4 pk4 = { f2bf(p0), f2bf(p1), f2bf(p2), f2bf(p3) };
        *(s16x4*)(psw + (lrow*128 + ((kb*32 + lg*8) ^ ((lrow&7)<<4)))) = pk4;
      }

      __builtin_amdgcn_s_setprio(1);
#pragma unroll
      for (int kp = 0; kp < 2; kp++){
        s16x8 pa = *(const s16x8*)(psw + (lrow*128 + ((kp*64 + lg*16) ^ ((lrow&7)<<4))));
#pragma unroll
        for (int dt = 0; dt < 8; dt++){
          int vrow = dt*16 + lrow;
          int vcolb = kp*64 + lg*16;
          s16x8 vf = *(const s16x8*)(vb_ + vrow*128 + (vcolb ^ ((vrow&7)<<4)));
          acc[dt] = mfma16(pa, vf, acc[dt]);
        }
      }
      __builtin_amdgcn_s_setprio(0);

      asm volatile("" ::: "memory");
      __builtin_amdgcn_s_barrier();
      asm volatile("" ::: "memory");
      const int gg = g + 2;
      if (gg < nTot){
        const int kvs = (gg < nA ? gg : gg - nA) * 64;
        STAGE_KV(g&1, kvs);
      }
    }

    float ls_ = lsum;
    ls_ += __shfl_xor(ls_, 16);
    ls_ += __shfl_xor(ls_, 32);
    float linv[4];
#pragma unroll
    for (int r = 0; r < 4; r++)
      linv[r] = 1.f / __shfl(ls_, (l & 48) | (lg*4 + r));
#pragma unroll
    for (int dt = 0; dt < 8; dt++){
#pragma unroll
      for (int r = 0; r < 4; r++){
        int nrow = qbw + lg*4 + r;
        int dcol = h*128 + dt*16 + lrow;
        attno[((size_t)b*2048 + nrow)*2048 + dcol] = f2bf(acc[dt][r] * linv[r]);
      }
    }
  }
#undef STAGE_KV
}

// ---------------- launch ----------------
extern "C" void kernel_launch(void* const* d_in, const int* in_sizes, int n_in,
                              void* d_out, int out_size, void* d_ws, size_t ws_size,
                              hipStream_t stream)
{
  const float* x    = (const float*)d_in[0];
  const float* pk   = (const float*)d_in[2];
  const float* pv   = (const float*)d_in[3];
  const float* Wqkv = (const float*)d_in[4];
  const float* bqkv = (const float*)d_in[5];
  const float* Wff  = (const float*)d_in[6];
  const float* bff  = (const float*)d_in[7];
  float* out   = (float*)d_out;
  float* kvout = out + 8388608;

  char* ws = (char*)d_ws;
  short* xb    = (short*)(ws);
  short* wqkvT = (short*)(ws + 16777216);
  short* wffT  = (short*)(ws + 41943040);
  short* qpre  = (short*)(ws + 50331648);
  short* kpre  = (short*)(ws + 67108864);
  short* vpre  = (short*)(ws + 83886080);
  short* krp   = (short*)(ws + 117440512);
  short* vTp   = (short*)(ws + 138412032);
  short* attno = (short*)(ws + 159383552);

  k_cvt_bf16<<<4096, TPB, 0, stream>>>(x, xb, 1048576);
  k_trans_cvt<<<dim3(64, 192), TPB, 0, stream>>>(Wqkv, wqkvT, 2048, 6144);
  k_trans_cvt<<<dim3(64, 64),  TPB, 0, stream>>>(Wff,  wffT,  2048, 2048);

  k_gemm8<0><<<dim3(16, 48), 512, 0, stream>>>(xb, wqkvT, 6144, 2048, bqkv,
                                               nullptr, kvout, qpre, kpre, vpre);

  k_rope_k_new<<<2048, TPB, 0, stream>>>(kpre, krp);
  k_rope_k_prefix<<<512, TPB, 0, stream>>>(pk, kvout, krp);
  k_v_prefix<<<512, TPB, 0, stream>>>(pv, kvout + (size_t)32*327680, vTp);
  k_v_new<<<2048, TPB, 0, stream>>>(vpre, vTp);

  k_attn<<<dim3(32, 16), TPB, 0, stream>>>(qpre, krp, vTp, attno);

  k_gemm8<1><<<dim3(16, 16), 512, 0, stream>>>(attno, wffT, 2048, 2048, bff,
                                               out, nullptr, nullptr, nullptr, nullptr);
}